// Round 1
// baseline (353.523 us; speedup 1.0000x reference)
//
#include <hip/hip_runtime.h>
#include <stdint.h>

#define NTREES 8
#define NNODES 5
#define CC 16
#define BB 8
#define HH 224
#define WW 224
#define NEGF (-1e30f)

struct Forest { int par[NTREES * NNODES]; };

// ---------------------------------------------------------------------------
// Host-side bit-exact reproduction of:
//   rng = np.random.default_rng(0)
//   p = [-1] + [int(rng.integers(0, i)) for i in range(1, NUM_NODES)]  (x8 trees)
// Chain: SeedSequence(0) -> PCG64 (XSL-RR 128/64) -> buffered next_uint32
//        -> Lemire-32 bounded sampling (numpy random_bounded_uint64_fill path).
// ---------------------------------------------------------------------------
namespace nprng {

struct Pcg {
  __uint128_t state, inc;
  int has_uint32;
  uint32_t uinteger;
};

static inline __uint128_t pcg_mult() {
  return (((__uint128_t)0x2360ED051FC65DA4ULL) << 64) | 0x4385DF649FCCF645ULL;
}

static inline void pcg_step(Pcg& s) { s.state = s.state * pcg_mult() + s.inc; }

static inline uint64_t pcg_next64(Pcg& s) {
  pcg_step(s);  // step THEN output (pcg_setseq_128_xsl_rr_64_random_r)
  uint64_t xored = (uint64_t)(s.state >> 64) ^ (uint64_t)s.state;
  unsigned rot = (unsigned)(s.state >> 122);
  return (xored >> rot) | (xored << ((64u - rot) & 63u));
}

static inline uint32_t pcg_next32(Pcg& s) {
  if (s.has_uint32) { s.has_uint32 = 0; return s.uinteger; }
  uint64_t n = pcg_next64(s);
  s.has_uint32 = 1;
  s.uinteger = (uint32_t)(n >> 32);   // high half buffered
  return (uint32_t)n;                 // low half returned first
}

// numpy buffered_bounded_lemire_uint32; rng = inclusive max (= high-1 here)
static inline uint32_t lemire32(Pcg& s, uint32_t rng) {
  const uint32_t rng_excl = rng + 1u;
  uint64_t m = (uint64_t)pcg_next32(s) * (uint64_t)rng_excl;
  uint32_t leftover = (uint32_t)m;
  if (leftover < rng_excl) {
    const uint32_t threshold = (uint32_t)((0xFFFFFFFFu - rng) % rng_excl);
    while (leftover < threshold) {
      m = (uint64_t)pcg_next32(s) * (uint64_t)rng_excl;
      leftover = (uint32_t)m;
    }
  }
  return (uint32_t)(m >> 32);
}

static void make_forest(Forest& f) {
  // --- SeedSequence(0): pool of 4 uint32, entropy = [0] ---
  const uint32_t INIT_A = 0x43b0d7e5u, MULT_A = 0x931e8875u;
  const uint32_t INIT_B = 0x8b51f9ddu, MULT_B = 0x58f38dedu;
  const uint32_t MIX_L  = 0xca01f9ddu, MIX_R  = 0x4973f715u;
  uint32_t pool[4];
  uint32_t hc = INIT_A;
  auto hashmix = [&](uint32_t v) -> uint32_t {
    v ^= hc; hc *= MULT_A; v *= hc; v ^= v >> 16; return v;
  };
  auto mix = [&](uint32_t x, uint32_t y) -> uint32_t {
    uint32_t r = MIX_L * x - MIX_R * y; r ^= r >> 16; return r;
  };
  pool[0] = hashmix(0u);                       // entropy word 0
  for (int i = 1; i < 4; ++i) pool[i] = hashmix(0u);
  for (int is = 0; is < 4; ++is)
    for (int id = 0; id < 4; ++id)
      if (is != id) pool[id] = mix(pool[id], hashmix(pool[is]));
  // generate_state(4, uint64) -> 8 uint32 words, cycled pool, hash chain B
  uint32_t st32[8];
  uint32_t hb = INIT_B;
  for (int i = 0; i < 8; ++i) {
    uint32_t dv = pool[i & 3];
    dv ^= hb; hb *= MULT_B; dv *= hb; dv ^= dv >> 16;
    st32[i] = dv;
  }
  uint64_t w64[4];
  for (int i = 0; i < 4; ++i)
    w64[i] = (uint64_t)st32[2 * i] | ((uint64_t)st32[2 * i + 1] << 32);  // LE view

  // --- PCG64 seeding: seed[0]=high of initstate, inc likewise ---
  __uint128_t initstate = (((__uint128_t)w64[0]) << 64) | w64[1];
  __uint128_t initseq   = (((__uint128_t)w64[2]) << 64) | w64[3];
  Pcg s;
  s.state = 0; s.inc = (initseq << 1) | 1;
  pcg_step(s);
  s.state += initstate;
  pcg_step(s);
  s.has_uint32 = 0; s.uinteger = 0;

  for (int t = 0; t < NTREES; ++t) {
    f.par[t * NNODES + 0] = -1;
    for (int i = 1; i < NNODES; ++i) {
      uint32_t rng = (uint32_t)(i - 1);  // integers(0, i): rng = high-1
      f.par[t * NNODES + i] = (rng == 0) ? 0 : (int)lemire32(s, rng);
    }
  }
}

}  // namespace nprng

// ---------------------------------------------------------------------------
// Device kernel: one wave per (b, c, tree). Streams rows h=0..223.
// State per non-root node j: prevM_j[w] = max_{h'<=h, w'<=w} v_j  (4 floats/lane).
// Per row: s_j = shift-right(prevM_j) (NEG into col 0);
//          v_i = xv + alpha_i + sum_{children j} s_j;
//          prevM_j = max(prevM_j, rowprefixmax(v_j));  root: racc = max(racc, v_0).
// ---------------------------------------------------------------------------
#define ADD4(d, s) { (d).x += (s).x; (d).y += (s).y; (d).z += (s).z; (d).w += (s).w; }
#define MAX4(d, s) { (d).x = fmaxf((d).x,(s).x); (d).y = fmaxf((d).y,(s).y); \
                     (d).z = fmaxf((d).z,(s).z); (d).w = fmaxf((d).w,(s).w); }

__global__ __launch_bounds__(64) void fis_kernel(const float* __restrict__ x,
                                                 const float* __restrict__ alphas,
                                                 float* __restrict__ out,
                                                 Forest f) {
  const int lane = threadIdx.x;
  const int blk  = blockIdx.x;
  const int t    = blk & (NTREES - 1);
  const int bc   = blk >> 3;            // b*16 + c
  const int c    = bc & (CC - 1);
  const int b    = bc >> 4;

  const float* __restrict__ xp = x + (size_t)bc * (HH * WW);

  const float a0 = alphas[(t * NNODES + 0) * CC + c];
  const float a1 = alphas[(t * NNODES + 1) * CC + c];
  const float a2 = alphas[(t * NNODES + 2) * CC + c];
  const float a3 = alphas[(t * NNODES + 3) * CC + c];
  const float a4 = alphas[(t * NNODES + 4) * CC + c];

  const int p1 = f.par[t * NNODES + 1];
  const int p2 = f.par[t * NNODES + 2];
  const int p3 = f.par[t * NNODES + 3];
  const int p4 = f.par[t * NNODES + 4];

  const int  w0     = lane * 4;
  const bool active = (w0 < WW);

  float4 pm1 = make_float4(NEGF, NEGF, NEGF, NEGF);
  float4 pm2 = pm1, pm3 = pm1, pm4 = pm1, racc = pm1;

  float4 xr = pm1;
  if (active) xr = *(const float4*)(xp + w0);

  // s_j[w] = prevM_j[w-1]; col 0 gets NEG
  auto shift1 = [&](const float4& pm) -> float4 {
    float up = __shfl_up(pm.w, 1);
    float s0 = (lane == 0) ? NEGF : up;
    return make_float4(s0, pm.x, pm.y, pm.z);
  };

  // prevM = max(prevM, inclusive row-prefix-max of v)
  auto scanupd = [&](const float4& v, float4& pm) {
    float l0 = v.x;
    float l1 = fmaxf(l0, v.y);
    float l2 = fmaxf(l1, v.z);
    float l3 = fmaxf(l2, v.w);
    float tot = l3;
#pragma unroll
    for (int d = 1; d < 64; d <<= 1)
      tot = fmaxf(tot, __shfl_up(tot, d));  // self-max is identity for lane<d
    float e = __shfl_up(tot, 1);
    e = (lane == 0) ? NEGF : e;
    pm.x = fmaxf(pm.x, fmaxf(e, l0));
    pm.y = fmaxf(pm.y, fmaxf(e, l1));
    pm.z = fmaxf(pm.z, fmaxf(e, l2));
    pm.w = fmaxf(pm.w, fmaxf(e, l3));
  };

  for (int h = 0; h < HH; ++h) {
    float4 xnext = make_float4(NEGF, NEGF, NEGF, NEGF);
    if (h + 1 < HH && active)
      xnext = *(const float4*)(xp + (size_t)(h + 1) * WW + w0);  // prefetch

    float4 xv;
    if (active) {
      xv.x = __logf(1.0f + fmaxf(xr.x, 0.0f));
      xv.y = __logf(1.0f + fmaxf(xr.y, 0.0f));
      xv.z = __logf(1.0f + fmaxf(xr.z, 0.0f));
      xv.w = __logf(1.0f + fmaxf(xr.w, 0.0f));
    } else {
      xv = make_float4(NEGF, NEGF, NEGF, NEGF);
    }

    float4 s1 = shift1(pm1);
    float4 s2 = shift1(pm2);
    float4 s3 = shift1(pm3);
    float4 s4 = shift1(pm4);

    float4 v0 = make_float4(xv.x + a0, xv.y + a0, xv.z + a0, xv.w + a0);
    float4 v1 = make_float4(xv.x + a1, xv.y + a1, xv.z + a1, xv.w + a1);
    float4 v2 = make_float4(xv.x + a2, xv.y + a2, xv.z + a2, xv.w + a2);
    float4 v3 = make_float4(xv.x + a3, xv.y + a3, xv.z + a3, xv.w + a3);
    float4 v4 = make_float4(xv.x + a4, xv.y + a4, xv.z + a4, xv.w + a4);

    // children contributions (s from previous rows -> any order is fine)
    if      (p4 == 0) ADD4(v0, s4) else if (p4 == 1) ADD4(v1, s4)
    else if (p4 == 2) ADD4(v2, s4) else              ADD4(v3, s4);
    if      (p3 == 0) ADD4(v0, s3) else if (p3 == 1) ADD4(v1, s3)
    else              ADD4(v2, s3);
    if      (p2 == 0) ADD4(v0, s2) else              ADD4(v1, s2);
    ADD4(v0, s1);  // p1 is always 0

    scanupd(v1, pm1);
    scanupd(v2, pm2);
    scanupd(v3, pm3);
    scanupd(v4, pm4);

    MAX4(racc, v0);
    xr = xnext;
  }

  float m = fmaxf(fmaxf(racc.x, racc.y), fmaxf(racc.z, racc.w));
#pragma unroll
  for (int d = 1; d < 64; d <<= 1) m = fmaxf(m, __shfl_xor(m, d));
  if (lane == 0) out[((size_t)b * NTREES + t) * CC + c] = expm1f(m);
}

extern "C" void kernel_launch(void* const* d_in, const int* in_sizes, int n_in,
                              void* d_out, int out_size, void* d_ws, size_t ws_size,
                              hipStream_t stream) {
  const float* x      = (const float*)d_in[0];
  const float* alphas = (const float*)d_in[1];
  float* out          = (float*)d_out;

  Forest f;
  nprng::make_forest(f);  // deterministic; same every call (graph-capture safe)

  dim3 grid(BB * CC * NTREES);  // 1024 blocks = one wave each
  dim3 block(64);
  hipLaunchKernelGGL(fis_kernel, grid, block, 0, stream, x, alphas, out, f);
}

// Round 2
// 231.703 us; speedup vs baseline: 1.5258x; 1.5258x over previous
//
#include <hip/hip_runtime.h>
#include <stdint.h>

#define NTREES 8
#define NNODES 5
#define CC 16
#define BB 8
#define HH 224
#define WW 224
#define NEGF (-1e30f)
#define LN2F 0.6931471805599453f

struct Forest { int par[NTREES * NNODES]; };

// ---------------------------------------------------------------------------
// Host-side bit-exact reproduction of np.random.default_rng(0) forest
// (verified absmax 0.0 vs numpy in round 1 — do not touch).
// ---------------------------------------------------------------------------
namespace nprng {

struct Pcg {
  __uint128_t state, inc;
  int has_uint32;
  uint32_t uinteger;
};

static inline __uint128_t pcg_mult() {
  return (((__uint128_t)0x2360ED051FC65DA4ULL) << 64) | 0x4385DF649FCCF645ULL;
}

static inline void pcg_step(Pcg& s) { s.state = s.state * pcg_mult() + s.inc; }

static inline uint64_t pcg_next64(Pcg& s) {
  pcg_step(s);
  uint64_t xored = (uint64_t)(s.state >> 64) ^ (uint64_t)s.state;
  unsigned rot = (unsigned)(s.state >> 122);
  return (xored >> rot) | (xored << ((64u - rot) & 63u));
}

static inline uint32_t pcg_next32(Pcg& s) {
  if (s.has_uint32) { s.has_uint32 = 0; return s.uinteger; }
  uint64_t n = pcg_next64(s);
  s.has_uint32 = 1;
  s.uinteger = (uint32_t)(n >> 32);
  return (uint32_t)n;
}

static inline uint32_t lemire32(Pcg& s, uint32_t rng) {
  const uint32_t rng_excl = rng + 1u;
  uint64_t m = (uint64_t)pcg_next32(s) * (uint64_t)rng_excl;
  uint32_t leftover = (uint32_t)m;
  if (leftover < rng_excl) {
    const uint32_t threshold = (uint32_t)((0xFFFFFFFFu - rng) % rng_excl);
    while (leftover < threshold) {
      m = (uint64_t)pcg_next32(s) * (uint64_t)rng_excl;
      leftover = (uint32_t)m;
    }
  }
  return (uint32_t)(m >> 32);
}

static void make_forest(Forest& f) {
  const uint32_t INIT_A = 0x43b0d7e5u, MULT_A = 0x931e8875u;
  const uint32_t INIT_B = 0x8b51f9ddu, MULT_B = 0x58f38dedu;
  const uint32_t MIX_L  = 0xca01f9ddu, MIX_R  = 0x4973f715u;
  uint32_t pool[4];
  uint32_t hc = INIT_A;
  auto hashmix = [&](uint32_t v) -> uint32_t {
    v ^= hc; hc *= MULT_A; v *= hc; v ^= v >> 16; return v;
  };
  auto mix = [&](uint32_t x, uint32_t y) -> uint32_t {
    uint32_t r = MIX_L * x - MIX_R * y; r ^= r >> 16; return r;
  };
  pool[0] = hashmix(0u);
  for (int i = 1; i < 4; ++i) pool[i] = hashmix(0u);
  for (int is = 0; is < 4; ++is)
    for (int id = 0; id < 4; ++id)
      if (is != id) pool[id] = mix(pool[id], hashmix(pool[is]));
  uint32_t st32[8];
  uint32_t hb = INIT_B;
  for (int i = 0; i < 8; ++i) {
    uint32_t dv = pool[i & 3];
    dv ^= hb; hb *= MULT_B; dv *= hb; dv ^= dv >> 16;
    st32[i] = dv;
  }
  uint64_t w64[4];
  for (int i = 0; i < 4; ++i)
    w64[i] = (uint64_t)st32[2 * i] | ((uint64_t)st32[2 * i + 1] << 32);

  __uint128_t initstate = (((__uint128_t)w64[0]) << 64) | w64[1];
  __uint128_t initseq   = (((__uint128_t)w64[2]) << 64) | w64[3];
  Pcg s;
  s.state = 0; s.inc = (initseq << 1) | 1;
  pcg_step(s);
  s.state += initstate;
  pcg_step(s);
  s.has_uint32 = 0; s.uinteger = 0;

  for (int t = 0; t < NTREES; ++t) {
    f.par[t * NNODES + 0] = -1;
    for (int i = 1; i < NNODES; ++i) {
      uint32_t rng = (uint32_t)(i - 1);
      f.par[t * NNODES + i] = (rng == 0) ? 0 : (int)lemire32(s, rng);
    }
  }
}

}  // namespace nprng

// ---------------------------------------------------------------------------
// DPP helpers — pure-VALU cross-lane (no ds_bpermute, no LDS).
// update_dpp: masked / source-invalid lanes return `old` = NEG (max identity).
// ---------------------------------------------------------------------------
template <int ctrl, int rm>
__device__ __forceinline__ float dpp_mov_neg(float x) {
  int r = __builtin_amdgcn_update_dpp(
      __builtin_bit_cast(int, NEGF), __builtin_bit_cast(int, x),
      ctrl, rm, 0xf, false);
  return __builtin_bit_cast(float, r);
}

// Inclusive 64-lane max-scan: GCN idiom, 6 dpp-max ops.
__device__ __forceinline__ float wave_incl_maxscan(float t) {
  t = fmaxf(t, dpp_mov_neg<0x111, 0xf>(t));  // row_shr:1
  t = fmaxf(t, dpp_mov_neg<0x112, 0xf>(t));  // row_shr:2
  t = fmaxf(t, dpp_mov_neg<0x114, 0xf>(t));  // row_shr:4
  t = fmaxf(t, dpp_mov_neg<0x118, 0xf>(t));  // row_shr:8
  t = fmaxf(t, dpp_mov_neg<0x142, 0xa>(t));  // row_bcast15 -> rows 1,3
  t = fmaxf(t, dpp_mov_neg<0x143, 0xc>(t));  // row_bcast31 -> rows 2,3
  return t;
}

// Shift whole wave right by 1 lane, NEG into lane 0.
__device__ __forceinline__ float wshr1(float t) {
  return dpp_mov_neg<0x138, 0xf>(t);  // wave_shr:1
}

#define ADD4(d, s) { (d).x += (s).x; (d).y += (s).y; (d).z += (s).z; (d).w += (s).w; }
#define MAX4(d, s) { (d).x = fmaxf((d).x,(s).x); (d).y = fmaxf((d).y,(s).y); \
                     (d).z = fmaxf((d).z,(s).z); (d).w = fmaxf((d).w,(s).w); }

// ---------------------------------------------------------------------------
// One wave per (tree, b, c). Alphas factored out (max-plus DP is
// translation-equivariant): DP runs on xv2 = log2(1+relu(x)) with alpha=0;
// epilogue: out = expm1(asum + ln2 * max_plane(V_root)).
// Block swizzle: t = blk>>7 so the 8 blocks sharing one x-plane are 128
// apart -> same XCD (round-robin mod 8) -> plane fetched once per L2.
// ---------------------------------------------------------------------------
__global__ __launch_bounds__(64) void fis_kernel(const float* __restrict__ x,
                                                 const float* __restrict__ alphas,
                                                 float* __restrict__ out,
                                                 Forest f) {
  const int lane = threadIdx.x;
  const int blk  = blockIdx.x;
  const int t    = blk >> 7;        // tree
  const int bc   = blk & 127;       // b*16 + c
  const int c    = bc & (CC - 1);
  const int b    = bc >> 4;

  const float* __restrict__ xp = x + (size_t)bc * (HH * WW);

  float asum = 0.f;
#pragma unroll
  for (int i = 0; i < NNODES; ++i) asum += alphas[(t * NNODES + i) * CC + c];

  const int p1 = f.par[t * NNODES + 1];  // always 0
  const int p2 = f.par[t * NNODES + 2];
  const int p3 = f.par[t * NNODES + 3];
  const int p4 = f.par[t * NNODES + 4];
  (void)p1;

  const int  w0     = lane * 4;
  const bool active = (w0 < WW);

  const float4 neg4 = make_float4(NEGF, NEGF, NEGF, NEGF);
  float4 pm1 = neg4, pm2 = neg4, pm3 = neg4, pm4 = neg4, racc = neg4;

  // Prefetch pipeline depth 2.
  float4 xa = neg4, xb = neg4;
  if (active) {
    xa = *(const float4*)(xp + w0);
    xb = *(const float4*)(xp + WW + w0);
  }

  auto shift1 = [&](const float4& pm) -> float4 {
    return make_float4(wshr1(pm.w), pm.x, pm.y, pm.z);
  };

  auto scanupd = [&](const float4& v, float4& pm) {
    float l0 = v.x;
    float l1 = fmaxf(l0, v.y);
    float l2 = fmaxf(l1, v.z);
    float l3 = fmaxf(l2, v.w);
    float q  = wave_incl_maxscan(l3);  // inclusive over lanes
    float e  = wshr1(q);               // exclusive (prev lanes)
    pm.x = fmaxf(pm.x, fmaxf(e, l0));
    pm.y = fmaxf(pm.y, fmaxf(e, l1));
    pm.z = fmaxf(pm.z, fmaxf(e, l2));
    pm.w = fmaxf(pm.w, q);
  };

#pragma unroll 2
  for (int h = 0; h < HH; ++h) {
    float4 xc = neg4;
    if (h + 2 < HH && active)
      xc = *(const float4*)(xp + (size_t)(h + 2) * WW + w0);

    float4 xv;
    if (active) {
      xv.x = __log2f(1.0f + fmaxf(xa.x, 0.0f));
      xv.y = __log2f(1.0f + fmaxf(xa.y, 0.0f));
      xv.z = __log2f(1.0f + fmaxf(xa.z, 0.0f));
      xv.w = __log2f(1.0f + fmaxf(xa.w, 0.0f));
    } else {
      xv = neg4;
    }

    float4 s1 = shift1(pm1);
    float4 s2 = shift1(pm2);
    float4 s3 = shift1(pm3);
    float4 s4 = shift1(pm4);

    float4 v0 = xv, v1 = xv, v2 = xv, v3 = xv, v4 = xv;
    (void)v4;

    // children contributions (s from rows < h -> order irrelevant)
    if      (p4 == 0) ADD4(v0, s4) else if (p4 == 1) ADD4(v1, s4)
    else if (p4 == 2) ADD4(v2, s4) else              ADD4(v3, s4);
    if      (p3 == 0) ADD4(v0, s3) else if (p3 == 1) ADD4(v1, s3)
    else              ADD4(v2, s3);
    if      (p2 == 0) ADD4(v0, s2) else              ADD4(v1, s2);
    ADD4(v0, s1);  // p1 is always 0

    scanupd(v1, pm1);
    scanupd(v2, pm2);
    scanupd(v3, pm3);
    scanupd(v4, pm4);

    MAX4(racc, v0);
    xa = xb; xb = xc;
  }

  float m = fmaxf(fmaxf(racc.x, racc.y), fmaxf(racc.z, racc.w));
#pragma unroll
  for (int d = 1; d < 64; d <<= 1) m = fmaxf(m, __shfl_xor(m, d));
  if (lane == 0)
    out[((size_t)b * NTREES + t) * CC + c] = expm1f(fmaf(m, LN2F, asum));
}

extern "C" void kernel_launch(void* const* d_in, const int* in_sizes, int n_in,
                              void* d_out, int out_size, void* d_ws, size_t ws_size,
                              hipStream_t stream) {
  const float* x      = (const float*)d_in[0];
  const float* alphas = (const float*)d_in[1];
  float* out          = (float*)d_out;

  Forest f;
  nprng::make_forest(f);  // deterministic; same every call (graph-capture safe)

  dim3 grid(BB * CC * NTREES);  // 1024 single-wave blocks
  dim3 block(64);
  hipLaunchKernelGGL(fis_kernel, grid, block, 0, stream, x, alphas, out, f);
}